// Round 2
// baseline (113.685 us; speedup 1.0000x reference)
//
#include <hip/hip_runtime.h>

// Median filter 1D, k=9, replicate padding. x: [B*C rows = 2048, L = 8192] fp32.
// Tile: 1024 outputs per 256-thread block (4 outputs/thread), LDS-staged with
// 4-element halo on each side. All window values kept in named scalars
// (NO local arrays -> no scratch spill; R1's 112us was ~800MB of scratch
// traffic from float w[12] whose address was taken).

#define TILE 1024
#define BLOCK 256
#define HALO 4   // (k-1)/2, k=9

__device__ __forceinline__ float med3(float a, float b, float c) {
    return __builtin_amdgcn_fmed3f(a, b, c);     // v_med3_f32
}
__device__ __forceinline__ float min3(float a, float b, float c) {
    return fminf(fminf(a, b), c);                // v_min3_f32
}
__device__ __forceinline__ float max3(float a, float b, float c) {
    return fmaxf(fmaxf(a, b), c);                // v_max3_f32
}

// Exact median of 9 in 13 ops: sort the three triples, then
// med3(max(lows), med(mids), min(highs)).
__device__ __forceinline__ float med9(float p0, float p1, float p2,
                                      float p3, float p4, float p5,
                                      float p6, float p7, float p8) {
    float l0 = min3(p0, p1, p2), m0 = med3(p0, p1, p2), h0 = max3(p0, p1, p2);
    float l1 = min3(p3, p4, p5), m1 = med3(p3, p4, p5), h1 = max3(p3, p4, p5);
    float l2 = min3(p6, p7, p8), m2 = med3(p6, p7, p8), h2 = max3(p6, p7, p8);
    return med3(max3(l0, l1, l2), med3(m0, m1, m2), min3(h0, h1, h2));
}

__global__ __launch_bounds__(BLOCK) void median9_kernel(
    const float* __restrict__ x, float* __restrict__ out, int L, int tilesPerRow) {
    __shared__ __align__(16) float s[TILE + 2 * HALO];

    const int tid = threadIdx.x;
    const int row = blockIdx.x / tilesPerRow;
    const int tile_start = (blockIdx.x % tilesPerRow) * TILE;
    const long long row_base = (long long)row * L;
    const float* xr = x + row_base;

    // Main coalesced load: 256 threads x float4 = 1024 floats (always in-row:
    // L is a multiple of TILE).
    float4 v = ((const float4*)(xr + tile_start))[tid];
    ((float4*)(s + HALO))[tid] = v;

    // Halo: 8 scalar loads with replicate-pad clamping.
    if (tid < 2 * HALO) {
        int pos, sidx;
        if (tid < HALO) {
            pos = tile_start - HALO + tid;
            sidx = tid;
        } else {
            pos = tile_start + TILE + (tid - HALO);
            sidx = TILE + HALO + (tid - HALO);
        }
        pos = min(max(pos, 0), L - 1);
        s[sidx] = xr[pos];
    }
    __syncthreads();

    // Each thread: 12 contiguous LDS floats (3x ds_read_b128) -> 4 medians.
    const float4* sv = (const float4*)(s + 4 * tid);   // 16B aligned
    float4 a = sv[0], b = sv[1], c = sv[2];

    float4 r;
    r.x = med9(a.x, a.y, a.z, a.w, b.x, b.y, b.z, b.w, c.x);
    r.y = med9(a.y, a.z, a.w, b.x, b.y, b.z, b.w, c.x, c.y);
    r.z = med9(a.z, a.w, b.x, b.y, b.z, b.w, c.x, c.y, c.z);
    r.w = med9(a.w, b.x, b.y, b.z, b.w, c.x, c.y, c.z, c.w);

    ((float4*)(out + row_base + tile_start))[tid] = r;
}

extern "C" void kernel_launch(void* const* d_in, const int* in_sizes, int n_in,
                              void* d_out, int out_size, void* d_ws, size_t ws_size,
                              hipStream_t stream) {
    const float* x = (const float*)d_in[0];
    float* out = (float*)d_out;
    const int L = 8192;                 // static per the reference setup
    const int rows = in_sizes[0] / L;   // 32*64 = 2048
    const int tilesPerRow = L / TILE;   // 8
    const int nblocks = rows * tilesPerRow;
    median9_kernel<<<nblocks, BLOCK, 0, stream>>>(x, out, L, tilesPerRow);
}